// Round 16
// baseline (255.446 us; speedup 1.0000x reference)
//
#include <hip/hip_runtime.h>
#include <hip/hip_bf16.h>

typedef __bf16 bf16x8 __attribute__((ext_vector_type(8)));
typedef float f32x16 __attribute__((ext_vector_type(16)));
typedef float f32x8 __attribute__((ext_vector_type(8)));
typedef float f32x2 __attribute__((ext_vector_type(2)));
typedef unsigned int u32;

#define MFMA32(a, b, c) __builtin_amdgcn_mfma_f32_32x32x16_bf16((a), (b), (c), 0, 0, 0)

__device__ __forceinline__ f32x16 zero16() {
  f32x16 z;
#pragma unroll
  for (int i = 0; i < 16; ++i) z[i] = 0.f;
  return z;
}

__device__ __forceinline__ unsigned short bfb(float f) {
  __hip_bfloat16 h = __float2bfloat16(f);
  return __builtin_bit_cast(unsigned short, h);
}
__device__ __forceinline__ u32 pk2(float lo, float hi) {
  return (u32)bfb(lo) | ((u32)bfb(hi) << 16);
}
__device__ __forceinline__ u32 pk2h(float lo, float hi) {
  _Float16 a = (_Float16)lo, b = (_Float16)hi;
  return (u32)__builtin_bit_cast(unsigned short, a) |
         ((u32)__builtin_bit_cast(unsigned short, b) << 16);
}
__device__ __forceinline__ bf16x8 ld8(const unsigned short* p) {
  return *reinterpret_cast<const bf16x8*>(p);
}
__device__ __forceinline__ void gld_lds16(const void* g, void* l) {
  __builtin_amdgcn_global_load_lds((const __attribute__((address_space(1))) void*)g,
                                   (__attribute__((address_space(3))) void*)l, 16, 0, 0);
}

// ---------------- fused prep: LN (8192 blocks) + wconv (320) + bias_gather (4096) ------
__global__ __launch_bounds__(256, 4) void prep_kernel(
    const float* __restrict__ x, const float* __restrict__ nw, const float* __restrict__ nb,
    unsigned short* __restrict__ xn, const float* __restrict__ qkv_w,
    const float* __restrict__ proj_w, unsigned short* __restrict__ wq,
    unsigned short* __restrict__ wp, const float* __restrict__ attn_biases,
    const int* __restrict__ bias_idxs, unsigned short* __restrict__ biasc) {
  int bid = blockIdx.x;
  if (bid < 8192) {
    // ---- LayerNorm: x (32768x256 f32) -> xn bf16
    int w = threadIdx.x >> 6, lane = threadIdx.x & 63;
    size_t row = (size_t)bid * 4 + w;
    float4 v = reinterpret_cast<const float4*>(x + row * 256)[lane];
    float s = (v.x + v.y) + (v.z + v.w);
    float q = (v.x * v.x + v.y * v.y) + (v.z * v.z + v.w * v.w);
#pragma unroll
    for (int m = 1; m < 64; m <<= 1) {
      s += __shfl_xor(s, m, 64);
      q += __shfl_xor(q, m, 64);
    }
    float mu = s * (1.f / 256.f);
    float var = fmaxf(q * (1.f / 256.f) - mu * mu, 0.f);
    float rs = rsqrtf(var + 1e-5f);
    float4 wv = reinterpret_cast<const float4*>(nw)[lane];
    float4 bv = reinterpret_cast<const float4*>(nb)[lane];
    float o0 = (v.x - mu) * rs * wv.x + bv.x;
    float o1 = (v.y - mu) * rs * wv.y + bv.y;
    float o2 = (v.z - mu) * rs * wv.z + bv.z;
    float o3 = (v.w - mu) * rs * wv.w + bv.w;
    uint2 o = make_uint2(pk2(o0, o1), pk2(o2, o3));
    reinterpret_cast<uint2*>(xn + row * 256)[lane] = o;
  } else if (bid < 8512) {
    // ---- weight convert f32 -> bf16
    int t = (bid - 8192) * 256 + threadIdx.x;  // 81920 total
    const int NQ = 49152;
    float4 v;
    unsigned short* dst;
    int idx;
    if (t < NQ) {
      v = reinterpret_cast<const float4*>(qkv_w)[t];
      dst = wq;
      idx = t;
    } else {
      v = reinterpret_cast<const float4*>(proj_w)[t - NQ];
      dst = wp;
      idx = t - NQ;
    }
    uint2 o = make_uint2(pk2(v.x, v.y), pk2(v.z, v.w));
    reinterpret_cast<uint2*>(dst)[idx] = o;
  } else {
    // ---- bias gather: coalesced lane-major f16 layout, pre-scaled by log2e
    int tt = (bid - 8512) * 256 + threadIdx.x;  // [0, 1<<20)
    int j8 = tt & 3;
    int lane = (tt >> 2) & 63;
    int t = (tt >> 8) & 15;
    int g = (tt >> 12) & 31;
    int h = tt >> 17;
    int q = g * 32 + (lane & 31);
    int lh = lane >> 5;
    int sub = j8 >> 1;
    int rb = (j8 & 1) * 16;
    const int* ir = bias_idxs + q * 1024 + (2 * t + sub) * 32 + 4 * lh + rb;
    int4 i0 = *reinterpret_cast<const int4*>(ir);
    int4 i1 = *reinterpret_cast<const int4*>(ir + 8);
    const float* tb = attn_biases + h * 1024;
    const float L2E = 1.4426950408889634f;
    uint4 o;
    o.x = pk2h(tb[i0.x] * L2E, tb[i0.y] * L2E);
    o.y = pk2h(tb[i0.z] * L2E, tb[i0.w] * L2E);
    o.z = pk2h(tb[i1.x] * L2E, tb[i1.y] * L2E);
    o.w = pk2h(tb[i1.z] * L2E, tb[i1.w] * L2E);
    reinterpret_cast<uint4*>(biasc)[tt] = o;
  }
}

// ---------------- shared GEMM core: C(128x128) += A(128xK) * B(128xK)^T, bf16, BK=128
template <int STAGES, int ROWB>
__device__ __forceinline__ void gemm_core(const char* Ag, const char* Bg, char* As, char* Bs,
                                          int m0, int n0, int w, int lane, f32x16 acc[2][2]) {
  int lr = lane & 31, lh = lane >> 5;
  for (int kb = 0; kb < STAGES; ++kb) {
    if (kb) __syncthreads();
#pragma unroll
    for (int i = 0; i < 8; ++i) {
      int ldsoff = (i * 4 + w) * 1024;        // wave-uniform LDS base
      int lflat = ldsoff + lane * 16;         // lane's actual dest
      int row = lflat >> 8;                   // 256B per LDS row
      int c = (lflat >> 4) & 15;              // 16B chunk in row
      int sc_ = (c ^ (row & 7)) << 4;         // source pre-swizzle (rule 21)
      gld_lds16(Ag + (size_t)(m0 + row) * ROWB + kb * 256 + sc_, As + ldsoff);
      gld_lds16(Bg + (size_t)(n0 + row) * ROWB + kb * 256 + sc_, Bs + ldsoff);
    }
    asm volatile("s_waitcnt vmcnt(0)" ::: "memory");
    __syncthreads();
    int ra = (w >> 1) * 64 + lr;
    int rb = (w & 1) * 64 + lr;
#pragma unroll
    for (int k16 = 0; k16 < 8; ++k16) {
      bf16x8 af[2], bfr[2];
#pragma unroll
      for (int i = 0; i < 2; ++i) {
        int rowa = ra + i * 32;
        int ca = (((k16 << 1) | lh) ^ (rowa & 7)) << 4;
        af[i] = *reinterpret_cast<const bf16x8*>(As + (rowa << 8) + ca);
        int rowb = rb + i * 32;
        int cb = (((k16 << 1) | lh) ^ (rowb & 7)) << 4;
        bfr[i] = *reinterpret_cast<const bf16x8*>(Bs + (rowb << 8) + cb);
      }
#pragma unroll
      for (int i = 0; i < 2; ++i)
#pragma unroll
        for (int j = 0; j < 2; ++j) acc[i][j] = MFMA32(af[i], bfr[j], acc[i][j]);
    }
  }
}

// ---------------- QKV GEMM: xn(32768x256) @ wq^T(256x768) -> scatter Q,K,Vt bf16
// V stored tiled: Vt[bh][t=32][c=4][d=64][e=8] with kv perm (bits 2<->3 of slot) baked in.
__global__ __launch_bounds__(256, 2) void qkv_gemm(const unsigned short* __restrict__ xn,
                                                   const unsigned short* __restrict__ wq,
                                                   const float* __restrict__ qkv_b,
                                                   unsigned short* __restrict__ Qb,
                                                   unsigned short* __restrict__ Kb,
                                                   unsigned short* __restrict__ Vt) {
  extern __shared__ char smem[];
  char* As = smem;
  char* Bs = smem + 32768;
  int bid = blockIdx.x;
  int f2 = (bid & 7) * 192 + (bid >> 3);  // XCD-bijective swizzle (1536 % 8 == 0)
  int nt = f2 % 6, mt = f2 / 6;
  int tid = threadIdx.x, w = tid >> 6, lane = tid & 63;
  int m0 = mt * 128, n0 = nt * 128;
  f32x16 acc[2][2];
  acc[0][0] = zero16(); acc[0][1] = zero16(); acc[1][0] = zero16(); acc[1][1] = zero16();
  gemm_core<2, 512>((const char*)xn, (const char*)wq, As, Bs, m0, n0, w, lane, acc);
  int lr = lane & 31, lh = lane >> 5;
#pragma unroll
  for (int j = 0; j < 2; ++j) {
    int col = n0 + (w & 1) * 64 + j * 32 + lr;  // qkv col 0..767
    int h = col / 96;
    int rr = col - h * 96;
    float bv = qkv_b[col];
#pragma unroll
    for (int i = 0; i < 2; ++i) {
      int rbase = m0 + (w >> 1) * 64 + i * 32 + 4 * lh;
      if (rr < 32) {  // Q or K: [bh][n][16]
        unsigned short* dst0 = (rr < 16) ? Qb : Kb;
        int cc = rr & 15;
#pragma unroll
        for (int r = 0; r < 16; ++r) {
          int n = rbase + (r & 3) + 8 * (r >> 2);
          int b = n >> 10, nn = n & 1023;
          dst0[(((size_t)(b * 8 + h) * 1024 + nn) << 4) + cc] = bfb(acc[i][j][r] + bv);
        }
      } else {  // V tiled + kv-permuted
        int d = rr - 32;
#pragma unroll
        for (int g = 0; g < 4; ++g) {
          int n = rbase + 8 * g;
          int b = n >> 10, nn = n & 1023;
          int t = nn >> 5, s0 = nn & 31;
          int s = (s0 & ~12) | ((s0 & 4) << 1) | ((s0 & 8) >> 1);  // swap bits 2,3
          size_t addr = ((size_t)(b * 8 + h) << 16) + t * 2048 + (s >> 3) * 512 + d * 8 + (s & 7);
          ushort4 pkv;
          pkv.x = bfb(acc[i][j][4 * g + 0] + bv);
          pkv.y = bfb(acc[i][j][4 * g + 1] + bv);
          pkv.z = bfb(acc[i][j][4 * g + 2] + bv);
          pkv.w = bfb(acc[i][j][4 * g + 3] + bv);
          *reinterpret_cast<ushort4*>(Vt + addr) = pkv;
        }
      }
    }
  }
}

// ---------------- fused attention: round-12 structure; (256,3) occupancy experiment ----
// Identical code to round 15 (72.3us @ 2 waves/SIMD, 112+64=176 regs). The ONLY change:
// __launch_bounds__(256,3) asks the allocator to shave ~8 arch VGPRs (112->~104) so
// total regs/wave <= ~170 -> 3 waves/SIMD. Tripwire: WRITE_SIZE >> 32MB = spill, revert.
__device__ __forceinline__ void stage_tile(const char* kgB, const char* vgB, char* buf,
                                           int t, int w, int lane) {
  const char* vsrc = vgB + (size_t)t * 8192;
  if (w < 2) {  // 3 DMAs: one K chunk + two V chunks
    gld_lds16(kgB + (size_t)t * 2048 + w * 1024 + lane * 16, buf + w * 1024);
    gld_lds16(vsrc + w * 1024 + lane * 16, buf + 2048 + w * 1024);
    gld_lds16(vsrc + (4 + w) * 1024 + lane * 16, buf + 2048 + (4 + w) * 1024);
  } else {  // 2 DMAs: two V chunks
    gld_lds16(vsrc + w * 1024 + lane * 16, buf + 2048 + w * 1024);
    gld_lds16(vsrc + (4 + w) * 1024 + lane * 16, buf + 2048 + (4 + w) * 1024);
  }
}

__device__ __forceinline__ bf16x8 cvt8(const float* p) {
  f32x8 v;
#pragma unroll
  for (int i = 0; i < 8; ++i) v[i] = p[i];
  return __builtin_convertvector(v, bf16x8);
}

__global__ __launch_bounds__(256, 3) void attn_kernel(const unsigned short* __restrict__ Qb,
                                                      const unsigned short* __restrict__ Kb,
                                                      const unsigned short* __restrict__ Vt,
                                                      const unsigned short* __restrict__ biasc,
                                                      unsigned short* __restrict__ aout) {
  extern __shared__ char smem[];  // 2 * (2KB K + 8KB V) = 20480 B
  int bid = blockIdx.x;
  int f2 = (bid & 7) * 128 + (bid >> 3);  // XCD x handles one h entirely (1024%8==0)
  int qt = f2 & 3, b = (f2 >> 2) & 31, h = f2 >> 7;
  int w = threadIdx.x >> 6, lane = threadIdx.x & 63;
  int lr = lane & 31, lh = lane >> 5;
  int bh = b * 8 + h;
  int q0 = qt * 256 + w * 64 + lr;  // group-0 q row; group 1 = +32
  bf16x8 qf0 = ld8(Qb + (((size_t)bh * 1024 + q0) << 4) + lh * 8);
  bf16x8 qf1 = ld8(Qb + (((size_t)bh * 1024 + q0 + 32) << 4) + lh * 8);
  const char* kgB = (const char*)Kb + ((size_t)bh << 15);
  const char* vgB = (const char*)Vt + ((size_t)bh << 17);
  int g0 = qt * 8 + w * 2;  // bias q-group index (q>>5)
  const char* bgB0 = (const char*)biasc + ((size_t)((h * 32 + g0) * 1024 + lane) << 6);
  const char* bgB1 = bgB0 + ((size_t)1024 << 6);
  f32x16 acc00 = zero16(), acc01 = zero16();  // group 0: d 0..31 / 32..63
  f32x16 acc10 = zero16(), acc11 = zero16();  // group 1
  f32x2 ls0 = {0.f, 0.f}, ls1 = {0.f, 0.f};
  const float SC = 0.25f * 1.4426950408889634f;  // scale * log2e

  stage_tile(kgB, vgB, smem, 0, w, lane);

  for (int t = 0; t < 16; ++t) {
    char* cur = smem + (t & 1) * 10240;
    char* nxt = smem + ((t + 1) & 1) * 10240;
    // tile-t DMAs were issued a full iteration ago -> drain is free
    asm volatile("s_waitcnt vmcnt(0)" ::: "memory");
    __builtin_amdgcn_sched_barrier(0);
    __builtin_amdgcn_s_barrier();
    __builtin_amdgcn_sched_barrier(0);
    // bias for tile t (coalesced 64B/lane per group; L2-resident, used after QK MFMAs)
    const char* bp0 = bgB0 + (size_t)t * 4096;
    const char* bp1 = bgB1 + (size_t)t * 4096;
    uint4 b00 = *reinterpret_cast<const uint4*>(bp0);
    uint4 b01 = *reinterpret_cast<const uint4*>(bp0 + 16);
    uint4 b02 = *reinterpret_cast<const uint4*>(bp0 + 32);
    uint4 b03 = *reinterpret_cast<const uint4*>(bp0 + 48);
    uint4 b10 = *reinterpret_cast<const uint4*>(bp1);
    uint4 b11 = *reinterpret_cast<const uint4*>(bp1 + 16);
    uint4 b12 = *reinterpret_cast<const uint4*>(bp1 + 32);
    uint4 b13 = *reinterpret_cast<const uint4*>(bp1 + 48);
    // LDS reads of tile t (shared across both q-groups -> per-work traffic halved)
    bf16x8 kf0 = *reinterpret_cast<const bf16x8*>(cur + lr * 32 + lh * 16);
    bf16x8 kf1 = *reinterpret_cast<const bf16x8*>(cur + 1024 + lr * 32 + lh * 16);
    const char* Vs = cur + 2048;
    bf16x8 va00 = *reinterpret_cast<const bf16x8*>(Vs + lh * 1024 + lr * 16);
    bf16x8 va10 = *reinterpret_cast<const bf16x8*>(Vs + (2 + lh) * 1024 + lr * 16);
    bf16x8 va01 = *reinterpret_cast<const bf16x8*>(Vs + lh * 1024 + 512 + lr * 16);
    bf16x8 va11 = *reinterpret_cast<const bf16x8*>(Vs + (2 + lh) * 1024 + 512 + lr * 16);
    bf16x8 vb00 = *reinterpret_cast<const bf16x8*>(Vs + 4096 + lh * 1024 + lr * 16);
    bf16x8 vb10 = *reinterpret_cast<const bf16x8*>(Vs + 4096 + (2 + lh) * 1024 + lr * 16);
    bf16x8 vb01 = *reinterpret_cast<const bf16x8*>(Vs + 4096 + lh * 1024 + 512 + lr * 16);
    bf16x8 vb11 = *reinterpret_cast<const bf16x8*>(Vs + 4096 + (2 + lh) * 1024 + 512 + lr * 16);
    // issue tile t+1 DMAs (post-barrier: no wave still reads buf[(t+1)&1])
    stage_tile(kgB, vgB, nxt, t + 1, w, lane);
    __builtin_amdgcn_sched_barrier(0);
    __builtin_amdgcn_s_setprio(1);
    f32x16 stA0 = MFMA32(kf0, qf0, zero16());
    f32x16 stB0 = MFMA32(kf1, qf0, zero16());
    f32x16 stA1 = MFMA32(kf0, qf1, zero16());
    f32x16 stB1 = MFMA32(kf1, qf1, zero16());
    union BB { uint4 u[2]; _Float16 hh[16]; };
    {  // group 0, subtile A
      BB bb; bb.u[0] = b00; bb.u[1] = b01;
      float p[16];
#pragma unroll
      for (int r = 0; r < 16; ++r)
        p[r] = __builtin_amdgcn_exp2f(fmaf(stA0[r], SC, (float)bb.hh[r]));
      bf16x8 a0 = cvt8(p), a1 = cvt8(p + 8);
      acc00 = MFMA32(a0, va00, acc00);
      acc01 = MFMA32(a0, va01, acc01);
      acc00 = MFMA32(a1, va10, acc00);
      acc01 = MFMA32(a1, va11, acc01);
#pragma unroll
      for (int i = 0; i < 8; ++i) { f32x2 e = {p[2 * i], p[2 * i + 1]}; ls0 += e; }
    }
    {  // group 0, subtile B
      BB bb; bb.u[0] = b02; bb.u[1] = b03;
      float p[16];
#pragma unroll
      for (int r = 0; r < 16; ++r)
        p[r] = __builtin_amdgcn_exp2f(fmaf(stB0[r], SC, (float)bb.hh[r]));
      bf16x8 a0 = cvt8(p), a1 = cvt8(p + 8);
      acc00 = MFMA32(a0, vb00, acc00);
      acc01 = MFMA32(a0, vb01, acc01);
      acc00 = MFMA32(a1, vb10, acc00);
      acc01 = MFMA32(a1, vb11, acc01);
#pragma unroll
      for (int i = 0; i < 8; ++i) { f32x2 e = {p[2 * i], p[2 * i + 1]}; ls0 += e; }
    }
    {  // group 1, subtile A
      BB bb; bb.u[0] = b10; bb.u[1] = b11;
      float p[16];
#pragma unroll
      for (int r = 0; r < 16; ++r)
        p[r] = __builtin_amdgcn_exp2f(fmaf(stA1[r], SC, (float)bb.hh[r]));
      bf16x8 a0 = cvt8(p), a1 = cvt8(p + 8);
      acc10 = MFMA32(a0, va00, acc10);
      acc11 = MFMA32(a0, va01, acc11);
      acc10 = MFMA32(a1, va10, acc10);
      acc11 = MFMA32(a1, va11, acc11);
#pragma unroll
      for (int i = 0; i < 8; ++i) { f32x2 e = {p[2 * i], p[2 * i + 1]}; ls1 += e; }
    }
    {  // group 1, subtile B
      BB bb; bb.u[0] = b12; bb.u[1] = b13;
      float p[16];
#pragma unroll
      for (int r = 0; r < 16; ++r)
        p[r] = __builtin_amdgcn_exp2f(fmaf(stB1[r], SC, (float)bb.hh[r]));
      bf16x8 a0 = cvt8(p), a1 = cvt8(p + 8);
      acc10 = MFMA32(a0, vb00, acc10);
      acc11 = MFMA32(a0, vb01, acc11);
      acc10 = MFMA32(a1, vb10, acc10);
      acc11 = MFMA32(a1, vb11, acc11);
#pragma unroll
      for (int i = 0; i < 8; ++i) { f32x2 e = {p[2 * i], p[2 * i + 1]}; ls1 += e; }
    }
    __builtin_amdgcn_s_setprio(0);
  }

  float l0 = ls0[0] + ls0[1];
  float s0 = l0 + __shfl_xor(l0, 32, 64);
  float inv0 = 1.f / s0;
  float l1 = ls1[0] + ls1[1];
  float s1 = l1 + __shfl_xor(l1, 32, 64);
  float inv1 = 1.f / s1;
  size_t ob0 = (((size_t)b << 10) + qt * 256 + w * 64) * 512 + h * 64;
  size_t ob1 = ob0 + (size_t)32 * 512;
#pragma unroll
  for (int r = 0; r < 16; ++r) {
    int qrow = (r & 3) + 8 * (r >> 2) + 4 * lh;
    float c0 = __shfl(inv0, qrow, 64);
    aout[ob0 + (size_t)qrow * 512 + lr] = bfb(acc00[r] * c0);
    aout[ob0 + (size_t)qrow * 512 + 32 + lr] = bfb(acc01[r] * c0);
    float c1 = __shfl(inv1, qrow, 64);
    aout[ob1 + (size_t)qrow * 512 + lr] = bfb(acc10[r] * c1);
    aout[ob1 + (size_t)qrow * 512 + 32 + lr] = bfb(acc11[r] * c1);
  }
}

// ---------------- proj GEMM: aout(32768x512 bf16) @ wp^T(512x256) + b -> f32 out
__global__ __launch_bounds__(256, 2) void proj_gemm(const unsigned short* __restrict__ Ain,
                                                    const unsigned short* __restrict__ wp,
                                                    const float* __restrict__ proj_b,
                                                    float* __restrict__ out) {
  extern __shared__ char smem[];
  char* As = smem;
  char* Bs = smem + 32768;
  int bid = blockIdx.x;
  int f2 = (bid & 7) * 64 + (bid >> 3);
  int nt = f2 & 1, mt = f2 >> 1;
  int tid = threadIdx.x, w = tid >> 6, lane = tid & 63;
  int m0 = mt * 128, n0 = nt * 128;
  f32x16 acc[2][2];
  acc[0][0] = zero16(); acc[0][1] = zero16(); acc[1][0] = zero16(); acc[1][1] = zero16();
  gemm_core<4, 1024>((const char*)Ain, (const char*)wp, As, Bs, m0, n0, w, lane, acc);
  int lr = lane & 31, lh = lane >> 5;
#pragma unroll
  for (int j = 0; j < 2; ++j) {
    int col = n0 + (w & 1) * 64 + j * 32 + lr;
    float pbv = proj_b[col];
#pragma unroll
    for (int i = 0; i < 2; ++i) {
      int rbase = m0 + (w >> 1) * 64 + i * 32 + 4 * lh;
#pragma unroll
      for (int r = 0; r < 16; ++r) {
        int n = rbase + (r & 3) + 8 * (r >> 2);
        out[(size_t)n * 256 + col] = acc[i][j][r] + pbv;
      }
    }
  }
}

extern "C" void kernel_launch(void* const* d_in, const int* in_sizes, int n_in,
                              void* d_out, int out_size, void* d_ws, size_t ws_size,
                              hipStream_t stream) {
  const float* x = (const float*)d_in[0];
  const float* norm_w = (const float*)d_in[1];
  const float* norm_b = (const float*)d_in[2];
  const float* qkv_w = (const float*)d_in[3];
  const float* qkv_b = (const float*)d_in[4];
  const float* proj_w = (const float*)d_in[5];
  const float* proj_b = (const float*)d_in[6];
  const float* attn_biases = (const float*)d_in[7];
  const int* bias_idxs = (const int*)d_in[8];
  float* out = (float*)d_out;
  char* ws = (char*)d_ws;
  // workspace layout (bytes), total ~118 MB (round-10 layout)
  unsigned short* xn = (unsigned short*)(ws + 0);          // 32768x256 bf16
  unsigned short* wq = (unsigned short*)(ws + 16777216);   // 768x256 bf16
  unsigned short* wp = (unsigned short*)(ws + 17170432);   // 256x512 bf16
  unsigned short* Qb = (unsigned short*)(ws + 17432576);   // [bh][1024][16]
  unsigned short* Kb = (unsigned short*)(ws + 25821184);   // [bh][1024][16]
  unsigned short* Vt = (unsigned short*)(ws + 34209792);   // [bh][32][4][64][8] kv-permuted tiles
  unsigned short* biasc = (unsigned short*)(ws + 67764224); // [8][32][16][64][32] f16 coalesced
  unsigned short* aout = (unsigned short*)(ws + 84541440);   // [32768][512]

  prep_kernel<<<12608, 256, 0, stream>>>(x, norm_w, norm_b, xn, qkv_w, proj_w, wq, wp,
                                         attn_biases, bias_idxs, biasc);
  qkv_gemm<<<1536, 256, 65536, stream>>>(xn, wq, qkv_b, Qb, Kb, Vt);
  attn_kernel<<<1024, 256, 20480, stream>>>(Qb, Kb, Vt, biasc, aout);
  proj_gemm<<<512, 256, 65536, stream>>>(aout, wp, proj_b, out);
}

// Round 17
// 125.386 us; speedup vs baseline: 2.0373x; 2.0373x over previous
//
#include <hip/hip_runtime.h>
#include <hip/hip_bf16.h>

typedef __bf16 bf16x8 __attribute__((ext_vector_type(8)));
typedef float f32x16 __attribute__((ext_vector_type(16)));
typedef float f32x8 __attribute__((ext_vector_type(8)));
typedef float f32x2 __attribute__((ext_vector_type(2)));
typedef unsigned int u32;

#define MFMA32(a, b, c) __builtin_amdgcn_mfma_f32_32x32x16_bf16((a), (b), (c), 0, 0, 0)

__device__ __forceinline__ f32x16 zero16() {
  f32x16 z;
#pragma unroll
  for (int i = 0; i < 16; ++i) z[i] = 0.f;
  return z;
}

__device__ __forceinline__ unsigned short bfb(float f) {
  __hip_bfloat16 h = __float2bfloat16(f);
  return __builtin_bit_cast(unsigned short, h);
}
__device__ __forceinline__ u32 pk2(float lo, float hi) {
  return (u32)bfb(lo) | ((u32)bfb(hi) << 16);
}
__device__ __forceinline__ u32 pk2h(float lo, float hi) {
  _Float16 a = (_Float16)lo, b = (_Float16)hi;
  return (u32)__builtin_bit_cast(unsigned short, a) |
         ((u32)__builtin_bit_cast(unsigned short, b) << 16);
}
__device__ __forceinline__ bf16x8 ld8(const unsigned short* p) {
  return *reinterpret_cast<const bf16x8*>(p);
}
__device__ __forceinline__ void gld_lds16(const void* g, void* l) {
  __builtin_amdgcn_global_load_lds((const __attribute__((address_space(1))) void*)g,
                                   (__attribute__((address_space(3))) void*)l, 16, 0, 0);
}

// ---------------- fused prep: LN (8192 blocks) + wconv (320) + bias_gather (4096) ------
__global__ __launch_bounds__(256, 4) void prep_kernel(
    const float* __restrict__ x, const float* __restrict__ nw, const float* __restrict__ nb,
    unsigned short* __restrict__ xn, const float* __restrict__ qkv_w,
    const float* __restrict__ proj_w, unsigned short* __restrict__ wq,
    unsigned short* __restrict__ wp, const float* __restrict__ attn_biases,
    const int* __restrict__ bias_idxs, unsigned short* __restrict__ biasc) {
  int bid = blockIdx.x;
  if (bid < 8192) {
    // ---- LayerNorm: x (32768x256 f32) -> xn bf16
    int w = threadIdx.x >> 6, lane = threadIdx.x & 63;
    size_t row = (size_t)bid * 4 + w;
    float4 v = reinterpret_cast<const float4*>(x + row * 256)[lane];
    float s = (v.x + v.y) + (v.z + v.w);
    float q = (v.x * v.x + v.y * v.y) + (v.z * v.z + v.w * v.w);
#pragma unroll
    for (int m = 1; m < 64; m <<= 1) {
      s += __shfl_xor(s, m, 64);
      q += __shfl_xor(q, m, 64);
    }
    float mu = s * (1.f / 256.f);
    float var = fmaxf(q * (1.f / 256.f) - mu * mu, 0.f);
    float rs = rsqrtf(var + 1e-5f);
    float4 wv = reinterpret_cast<const float4*>(nw)[lane];
    float4 bv = reinterpret_cast<const float4*>(nb)[lane];
    float o0 = (v.x - mu) * rs * wv.x + bv.x;
    float o1 = (v.y - mu) * rs * wv.y + bv.y;
    float o2 = (v.z - mu) * rs * wv.z + bv.z;
    float o3 = (v.w - mu) * rs * wv.w + bv.w;
    uint2 o = make_uint2(pk2(o0, o1), pk2(o2, o3));
    reinterpret_cast<uint2*>(xn + row * 256)[lane] = o;
  } else if (bid < 8512) {
    // ---- weight convert f32 -> bf16
    int t = (bid - 8192) * 256 + threadIdx.x;  // 81920 total
    const int NQ = 49152;
    float4 v;
    unsigned short* dst;
    int idx;
    if (t < NQ) {
      v = reinterpret_cast<const float4*>(qkv_w)[t];
      dst = wq;
      idx = t;
    } else {
      v = reinterpret_cast<const float4*>(proj_w)[t - NQ];
      dst = wp;
      idx = t - NQ;
    }
    uint2 o = make_uint2(pk2(v.x, v.y), pk2(v.z, v.w));
    reinterpret_cast<uint2*>(dst)[idx] = o;
  } else {
    // ---- bias gather: coalesced lane-major f16 layout, pre-scaled by log2e
    int tt = (bid - 8512) * 256 + threadIdx.x;  // [0, 1<<20)
    int j8 = tt & 3;
    int lane = (tt >> 2) & 63;
    int t = (tt >> 8) & 15;
    int g = (tt >> 12) & 31;
    int h = tt >> 17;
    int q = g * 32 + (lane & 31);
    int lh = lane >> 5;
    int sub = j8 >> 1;
    int rb = (j8 & 1) * 16;
    const int* ir = bias_idxs + q * 1024 + (2 * t + sub) * 32 + 4 * lh + rb;
    int4 i0 = *reinterpret_cast<const int4*>(ir);
    int4 i1 = *reinterpret_cast<const int4*>(ir + 8);
    const float* tb = attn_biases + h * 1024;
    const float L2E = 1.4426950408889634f;
    uint4 o;
    o.x = pk2h(tb[i0.x] * L2E, tb[i0.y] * L2E);
    o.y = pk2h(tb[i0.z] * L2E, tb[i0.w] * L2E);
    o.z = pk2h(tb[i1.x] * L2E, tb[i1.y] * L2E);
    o.w = pk2h(tb[i1.z] * L2E, tb[i1.w] * L2E);
    reinterpret_cast<uint4*>(biasc)[tt] = o;
  }
}

// ---------------- shared GEMM core: C(128x128) += A(128xK) * B(128xK)^T, bf16, BK=128
template <int STAGES, int ROWB>
__device__ __forceinline__ void gemm_core(const char* Ag, const char* Bg, char* As, char* Bs,
                                          int m0, int n0, int w, int lane, f32x16 acc[2][2]) {
  int lr = lane & 31, lh = lane >> 5;
  for (int kb = 0; kb < STAGES; ++kb) {
    if (kb) __syncthreads();
#pragma unroll
    for (int i = 0; i < 8; ++i) {
      int ldsoff = (i * 4 + w) * 1024;        // wave-uniform LDS base
      int lflat = ldsoff + lane * 16;         // lane's actual dest
      int row = lflat >> 8;                   // 256B per LDS row
      int c = (lflat >> 4) & 15;              // 16B chunk in row
      int sc_ = (c ^ (row & 7)) << 4;         // source pre-swizzle (rule 21)
      gld_lds16(Ag + (size_t)(m0 + row) * ROWB + kb * 256 + sc_, As + ldsoff);
      gld_lds16(Bg + (size_t)(n0 + row) * ROWB + kb * 256 + sc_, Bs + ldsoff);
    }
    asm volatile("s_waitcnt vmcnt(0)" ::: "memory");
    __syncthreads();
    int ra = (w >> 1) * 64 + lr;
    int rb = (w & 1) * 64 + lr;
#pragma unroll
    for (int k16 = 0; k16 < 8; ++k16) {
      bf16x8 af[2], bfr[2];
#pragma unroll
      for (int i = 0; i < 2; ++i) {
        int rowa = ra + i * 32;
        int ca = (((k16 << 1) | lh) ^ (rowa & 7)) << 4;
        af[i] = *reinterpret_cast<const bf16x8*>(As + (rowa << 8) + ca);
        int rowb = rb + i * 32;
        int cb = (((k16 << 1) | lh) ^ (rowb & 7)) << 4;
        bfr[i] = *reinterpret_cast<const bf16x8*>(Bs + (rowb << 8) + cb);
      }
#pragma unroll
      for (int i = 0; i < 2; ++i)
#pragma unroll
        for (int j = 0; j < 2; ++j) acc[i][j] = MFMA32(af[i], bfr[j], acc[i][j]);
    }
  }
}

// ---------------- QKV GEMM: xn(32768x256) @ wq^T(256x768) -> scatter Q,K,Vt bf16
// V stored tiled: Vt[bh][t=32][c=4][d=64][e=8] with kv perm (bits 2<->3 of slot) baked in.
__global__ __launch_bounds__(256, 2) void qkv_gemm(const unsigned short* __restrict__ xn,
                                                   const unsigned short* __restrict__ wq,
                                                   const float* __restrict__ qkv_b,
                                                   unsigned short* __restrict__ Qb,
                                                   unsigned short* __restrict__ Kb,
                                                   unsigned short* __restrict__ Vt) {
  extern __shared__ char smem[];
  char* As = smem;
  char* Bs = smem + 32768;
  int bid = blockIdx.x;
  int f2 = (bid & 7) * 192 + (bid >> 3);  // XCD-bijective swizzle (1536 % 8 == 0)
  int nt = f2 % 6, mt = f2 / 6;
  int tid = threadIdx.x, w = tid >> 6, lane = tid & 63;
  int m0 = mt * 128, n0 = nt * 128;
  f32x16 acc[2][2];
  acc[0][0] = zero16(); acc[0][1] = zero16(); acc[1][0] = zero16(); acc[1][1] = zero16();
  gemm_core<2, 512>((const char*)xn, (const char*)wq, As, Bs, m0, n0, w, lane, acc);
  int lr = lane & 31, lh = lane >> 5;
#pragma unroll
  for (int j = 0; j < 2; ++j) {
    int col = n0 + (w & 1) * 64 + j * 32 + lr;  // qkv col 0..767
    int h = col / 96;
    int rr = col - h * 96;
    float bv = qkv_b[col];
#pragma unroll
    for (int i = 0; i < 2; ++i) {
      int rbase = m0 + (w >> 1) * 64 + i * 32 + 4 * lh;
      if (rr < 32) {  // Q or K: [bh][n][16]
        unsigned short* dst0 = (rr < 16) ? Qb : Kb;
        int cc = rr & 15;
#pragma unroll
        for (int r = 0; r < 16; ++r) {
          int n = rbase + (r & 3) + 8 * (r >> 2);
          int b = n >> 10, nn = n & 1023;
          dst0[(((size_t)(b * 8 + h) * 1024 + nn) << 4) + cc] = bfb(acc[i][j][r] + bv);
        }
      } else {  // V tiled + kv-permuted
        int d = rr - 32;
#pragma unroll
        for (int g = 0; g < 4; ++g) {
          int n = rbase + 8 * g;
          int b = n >> 10, nn = n & 1023;
          int t = nn >> 5, s0 = nn & 31;
          int s = (s0 & ~12) | ((s0 & 4) << 1) | ((s0 & 8) >> 1);  // swap bits 2,3
          size_t addr = ((size_t)(b * 8 + h) << 16) + t * 2048 + (s >> 3) * 512 + d * 8 + (s & 7);
          ushort4 pkv;
          pkv.x = bfb(acc[i][j][4 * g + 0] + bv);
          pkv.y = bfb(acc[i][j][4 * g + 1] + bv);
          pkv.z = bfb(acc[i][j][4 * g + 2] + bv);
          pkv.w = bfb(acc[i][j][4 * g + 3] + bv);
          *reinterpret_cast<ushort4*>(Vt + addr) = pkv;
        }
      }
    }
  }
}

// ---------------- fused attention: round-12/15 structure (best known: 72.1us) ----------
// 2 q-groups (64 q rows) per wave, 256-thread blocks, grid 1024. KVBLK=64, one
// barrier/iter; all 4 QK MFMAs issued up front (ILP over the exp2 chains). Bias f16
// frag-order coalesced, loaded inside the iter. REGISTER-PRESSURE LEDGER (measured):
// (256,2) -> 112 arch VGPR + 64 acc = 176/wave, 2 waves/SIMD, no spill  [r12/r15 BEST]
// (256,3) -> allocator hits 84 and SPILLS (WRITE 32->310MB, 3x slower)  [r16 ✗]
// (256,4) -> 64-VGPR cap, catastrophic spill                            [r6/r8 ✗]
// deferring group-1 work (less pressure, less ILP) -> 80us              [r14 ✗]
__device__ __forceinline__ void stage_tile(const char* kgB, const char* vgB, char* buf,
                                           int t, int w, int lane) {
  const char* vsrc = vgB + (size_t)t * 8192;
  if (w < 2) {  // 3 DMAs: one K chunk + two V chunks
    gld_lds16(kgB + (size_t)t * 2048 + w * 1024 + lane * 16, buf + w * 1024);
    gld_lds16(vsrc + w * 1024 + lane * 16, buf + 2048 + w * 1024);
    gld_lds16(vsrc + (4 + w) * 1024 + lane * 16, buf + 2048 + (4 + w) * 1024);
  } else {  // 2 DMAs: two V chunks
    gld_lds16(vsrc + w * 1024 + lane * 16, buf + 2048 + w * 1024);
    gld_lds16(vsrc + (4 + w) * 1024 + lane * 16, buf + 2048 + (4 + w) * 1024);
  }
}

__device__ __forceinline__ bf16x8 cvt8(const float* p) {
  f32x8 v;
#pragma unroll
  for (int i = 0; i < 8; ++i) v[i] = p[i];
  return __builtin_convertvector(v, bf16x8);
}

__global__ __launch_bounds__(256, 2) void attn_kernel(const unsigned short* __restrict__ Qb,
                                                      const unsigned short* __restrict__ Kb,
                                                      const unsigned short* __restrict__ Vt,
                                                      const unsigned short* __restrict__ biasc,
                                                      unsigned short* __restrict__ aout) {
  extern __shared__ char smem[];  // 2 * (2KB K + 8KB V) = 20480 B
  int bid = blockIdx.x;
  int f2 = (bid & 7) * 128 + (bid >> 3);  // XCD x handles one h entirely (1024%8==0)
  int qt = f2 & 3, b = (f2 >> 2) & 31, h = f2 >> 7;
  int w = threadIdx.x >> 6, lane = threadIdx.x & 63;
  int lr = lane & 31, lh = lane >> 5;
  int bh = b * 8 + h;
  int q0 = qt * 256 + w * 64 + lr;  // group-0 q row; group 1 = +32
  bf16x8 qf0 = ld8(Qb + (((size_t)bh * 1024 + q0) << 4) + lh * 8);
  bf16x8 qf1 = ld8(Qb + (((size_t)bh * 1024 + q0 + 32) << 4) + lh * 8);
  const char* kgB = (const char*)Kb + ((size_t)bh << 15);
  const char* vgB = (const char*)Vt + ((size_t)bh << 17);
  int g0 = qt * 8 + w * 2;  // bias q-group index (q>>5)
  const char* bgB0 = (const char*)biasc + ((size_t)((h * 32 + g0) * 1024 + lane) << 6);
  const char* bgB1 = bgB0 + ((size_t)1024 << 6);
  f32x16 acc00 = zero16(), acc01 = zero16();  // group 0: d 0..31 / 32..63
  f32x16 acc10 = zero16(), acc11 = zero16();  // group 1
  f32x2 ls0 = {0.f, 0.f}, ls1 = {0.f, 0.f};
  const float SC = 0.25f * 1.4426950408889634f;  // scale * log2e

  stage_tile(kgB, vgB, smem, 0, w, lane);

  for (int t = 0; t < 16; ++t) {
    char* cur = smem + (t & 1) * 10240;
    char* nxt = smem + ((t + 1) & 1) * 10240;
    // tile-t DMAs were issued a full iteration ago -> drain is free
    asm volatile("s_waitcnt vmcnt(0)" ::: "memory");
    __builtin_amdgcn_sched_barrier(0);
    __builtin_amdgcn_s_barrier();
    __builtin_amdgcn_sched_barrier(0);
    // bias for tile t (coalesced 64B/lane per group; L2-resident, used after QK MFMAs)
    const char* bp0 = bgB0 + (size_t)t * 4096;
    const char* bp1 = bgB1 + (size_t)t * 4096;
    uint4 b00 = *reinterpret_cast<const uint4*>(bp0);
    uint4 b01 = *reinterpret_cast<const uint4*>(bp0 + 16);
    uint4 b02 = *reinterpret_cast<const uint4*>(bp0 + 32);
    uint4 b03 = *reinterpret_cast<const uint4*>(bp0 + 48);
    uint4 b10 = *reinterpret_cast<const uint4*>(bp1);
    uint4 b11 = *reinterpret_cast<const uint4*>(bp1 + 16);
    uint4 b12 = *reinterpret_cast<const uint4*>(bp1 + 32);
    uint4 b13 = *reinterpret_cast<const uint4*>(bp1 + 48);
    // LDS reads of tile t (shared across both q-groups -> per-work traffic halved)
    bf16x8 kf0 = *reinterpret_cast<const bf16x8*>(cur + lr * 32 + lh * 16);
    bf16x8 kf1 = *reinterpret_cast<const bf16x8*>(cur + 1024 + lr * 32 + lh * 16);
    const char* Vs = cur + 2048;
    bf16x8 va00 = *reinterpret_cast<const bf16x8*>(Vs + lh * 1024 + lr * 16);
    bf16x8 va10 = *reinterpret_cast<const bf16x8*>(Vs + (2 + lh) * 1024 + lr * 16);
    bf16x8 va01 = *reinterpret_cast<const bf16x8*>(Vs + lh * 1024 + 512 + lr * 16);
    bf16x8 va11 = *reinterpret_cast<const bf16x8*>(Vs + (2 + lh) * 1024 + 512 + lr * 16);
    bf16x8 vb00 = *reinterpret_cast<const bf16x8*>(Vs + 4096 + lh * 1024 + lr * 16);
    bf16x8 vb10 = *reinterpret_cast<const bf16x8*>(Vs + 4096 + (2 + lh) * 1024 + lr * 16);
    bf16x8 vb01 = *reinterpret_cast<const bf16x8*>(Vs + 4096 + lh * 1024 + 512 + lr * 16);
    bf16x8 vb11 = *reinterpret_cast<const bf16x8*>(Vs + 4096 + (2 + lh) * 1024 + 512 + lr * 16);
    // issue tile t+1 DMAs (post-barrier: no wave still reads buf[(t+1)&1])
    stage_tile(kgB, vgB, nxt, t + 1, w, lane);
    __builtin_amdgcn_sched_barrier(0);
    __builtin_amdgcn_s_setprio(1);
    f32x16 stA0 = MFMA32(kf0, qf0, zero16());
    f32x16 stB0 = MFMA32(kf1, qf0, zero16());
    f32x16 stA1 = MFMA32(kf0, qf1, zero16());
    f32x16 stB1 = MFMA32(kf1, qf1, zero16());
    union BB { uint4 u[2]; _Float16 hh[16]; };
    {  // group 0, subtile A
      BB bb; bb.u[0] = b00; bb.u[1] = b01;
      float p[16];
#pragma unroll
      for (int r = 0; r < 16; ++r)
        p[r] = __builtin_amdgcn_exp2f(fmaf(stA0[r], SC, (float)bb.hh[r]));
      bf16x8 a0 = cvt8(p), a1 = cvt8(p + 8);
      acc00 = MFMA32(a0, va00, acc00);
      acc01 = MFMA32(a0, va01, acc01);
      acc00 = MFMA32(a1, va10, acc00);
      acc01 = MFMA32(a1, va11, acc01);
#pragma unroll
      for (int i = 0; i < 8; ++i) { f32x2 e = {p[2 * i], p[2 * i + 1]}; ls0 += e; }
    }
    {  // group 0, subtile B
      BB bb; bb.u[0] = b02; bb.u[1] = b03;
      float p[16];
#pragma unroll
      for (int r = 0; r < 16; ++r)
        p[r] = __builtin_amdgcn_exp2f(fmaf(stB0[r], SC, (float)bb.hh[r]));
      bf16x8 a0 = cvt8(p), a1 = cvt8(p + 8);
      acc00 = MFMA32(a0, vb00, acc00);
      acc01 = MFMA32(a0, vb01, acc01);
      acc00 = MFMA32(a1, vb10, acc00);
      acc01 = MFMA32(a1, vb11, acc01);
#pragma unroll
      for (int i = 0; i < 8; ++i) { f32x2 e = {p[2 * i], p[2 * i + 1]}; ls0 += e; }
    }
    {  // group 1, subtile A
      BB bb; bb.u[0] = b10; bb.u[1] = b11;
      float p[16];
#pragma unroll
      for (int r = 0; r < 16; ++r)
        p[r] = __builtin_amdgcn_exp2f(fmaf(stA1[r], SC, (float)bb.hh[r]));
      bf16x8 a0 = cvt8(p), a1 = cvt8(p + 8);
      acc10 = MFMA32(a0, va00, acc10);
      acc11 = MFMA32(a0, va01, acc11);
      acc10 = MFMA32(a1, va10, acc10);
      acc11 = MFMA32(a1, va11, acc11);
#pragma unroll
      for (int i = 0; i < 8; ++i) { f32x2 e = {p[2 * i], p[2 * i + 1]}; ls1 += e; }
    }
    {  // group 1, subtile B
      BB bb; bb.u[0] = b12; bb.u[1] = b13;
      float p[16];
#pragma unroll
      for (int r = 0; r < 16; ++r)
        p[r] = __builtin_amdgcn_exp2f(fmaf(stB1[r], SC, (float)bb.hh[r]));
      bf16x8 a0 = cvt8(p), a1 = cvt8(p + 8);
      acc10 = MFMA32(a0, vb00, acc10);
      acc11 = MFMA32(a0, vb01, acc11);
      acc10 = MFMA32(a1, vb10, acc10);
      acc11 = MFMA32(a1, vb11, acc11);
#pragma unroll
      for (int i = 0; i < 8; ++i) { f32x2 e = {p[2 * i], p[2 * i + 1]}; ls1 += e; }
    }
    __builtin_amdgcn_s_setprio(0);
  }

  float l0 = ls0[0] + ls0[1];
  float s0 = l0 + __shfl_xor(l0, 32, 64);
  float inv0 = 1.f / s0;
  float l1 = ls1[0] + ls1[1];
  float s1 = l1 + __shfl_xor(l1, 32, 64);
  float inv1 = 1.f / s1;
  size_t ob0 = (((size_t)b << 10) + qt * 256 + w * 64) * 512 + h * 64;
  size_t ob1 = ob0 + (size_t)32 * 512;
#pragma unroll
  for (int r = 0; r < 16; ++r) {
    int qrow = (r & 3) + 8 * (r >> 2) + 4 * lh;
    float c0 = __shfl(inv0, qrow, 64);
    aout[ob0 + (size_t)qrow * 512 + lr] = bfb(acc00[r] * c0);
    aout[ob0 + (size_t)qrow * 512 + 32 + lr] = bfb(acc01[r] * c0);
    float c1 = __shfl(inv1, qrow, 64);
    aout[ob1 + (size_t)qrow * 512 + lr] = bfb(acc10[r] * c1);
    aout[ob1 + (size_t)qrow * 512 + 32 + lr] = bfb(acc11[r] * c1);
  }
}

// ---------------- proj GEMM: aout(32768x512 bf16) @ wp^T(512x256) + b -> f32 out
__global__ __launch_bounds__(256, 2) void proj_gemm(const unsigned short* __restrict__ Ain,
                                                    const unsigned short* __restrict__ wp,
                                                    const float* __restrict__ proj_b,
                                                    float* __restrict__ out) {
  extern __shared__ char smem[];
  char* As = smem;
  char* Bs = smem + 32768;
  int bid = blockIdx.x;
  int f2 = (bid & 7) * 64 + (bid >> 3);
  int nt = f2 & 1, mt = f2 >> 1;
  int tid = threadIdx.x, w = tid >> 6, lane = tid & 63;
  int m0 = mt * 128, n0 = nt * 128;
  f32x16 acc[2][2];
  acc[0][0] = zero16(); acc[0][1] = zero16(); acc[1][0] = zero16(); acc[1][1] = zero16();
  gemm_core<4, 1024>((const char*)Ain, (const char*)wp, As, Bs, m0, n0, w, lane, acc);
  int lr = lane & 31, lh = lane >> 5;
#pragma unroll
  for (int j = 0; j < 2; ++j) {
    int col = n0 + (w & 1) * 64 + j * 32 + lr;
    float pbv = proj_b[col];
#pragma unroll
    for (int i = 0; i < 2; ++i) {
      int rbase = m0 + (w >> 1) * 64 + i * 32 + 4 * lh;
#pragma unroll
      for (int r = 0; r < 16; ++r) {
        int n = rbase + (r & 3) + 8 * (r >> 2);
        out[(size_t)n * 256 + col] = acc[i][j][r] + pbv;
      }
    }
  }
}

extern "C" void kernel_launch(void* const* d_in, const int* in_sizes, int n_in,
                              void* d_out, int out_size, void* d_ws, size_t ws_size,
                              hipStream_t stream) {
  const float* x = (const float*)d_in[0];
  const float* norm_w = (const float*)d_in[1];
  const float* norm_b = (const float*)d_in[2];
  const float* qkv_w = (const float*)d_in[3];
  const float* qkv_b = (const float*)d_in[4];
  const float* proj_w = (const float*)d_in[5];
  const float* proj_b = (const float*)d_in[6];
  const float* attn_biases = (const float*)d_in[7];
  const int* bias_idxs = (const int*)d_in[8];
  float* out = (float*)d_out;
  char* ws = (char*)d_ws;
  // workspace layout (bytes), total ~118 MB (round-10 layout)
  unsigned short* xn = (unsigned short*)(ws + 0);          // 32768x256 bf16
  unsigned short* wq = (unsigned short*)(ws + 16777216);   // 768x256 bf16
  unsigned short* wp = (unsigned short*)(ws + 17170432);   // 256x512 bf16
  unsigned short* Qb = (unsigned short*)(ws + 17432576);   // [bh][1024][16]
  unsigned short* Kb = (unsigned short*)(ws + 25821184);   // [bh][1024][16]
  unsigned short* Vt = (unsigned short*)(ws + 34209792);   // [bh][32][4][64][8] kv-permuted tiles
  unsigned short* biasc = (unsigned short*)(ws + 67764224); // [8][32][16][64][32] f16 coalesced
  unsigned short* aout = (unsigned short*)(ws + 84541440);   // [32768][512]

  prep_kernel<<<12608, 256, 0, stream>>>(x, norm_w, norm_b, xn, qkv_w, proj_w, wq, wp,
                                         attn_biases, bias_idxs, biasc);
  qkv_gemm<<<1536, 256, 65536, stream>>>(xn, wq, qkv_b, Qb, Kb, Vt);
  attn_kernel<<<1024, 256, 20480, stream>>>(Qb, Kb, Vt, biasc, aout);
  proj_gemm<<<512, 256, 65536, stream>>>(aout, wp, proj_b, out);
}